// Round 2
// baseline (146.551 us; speedup 1.0000x reference)
//
#include <hip/hip_runtime.h>
#include <hip/hip_cooperative_groups.h>

namespace cg = cooperative_groups;

// FAVOR+ causal linear attention, fully fused cooperative kernel.
// BH=8, D=DV=64, N=2048, M=128, chunk C=64, NC=32. 256 blocks = 1 block/CU.
// Phase A: per-chunk phi (Q,K in both layouts), S^T chunk-local -> global,
//          z -> global, intra-chunk causal C=phiQ.phiK^T (masked) and E=C.V.
// grid.sync -> Phase B: exclusive prefix scan of S^T (bf16) and z (fp32).
// grid.sync -> Phase C: accO += phiQ.S_excl, norm += phiQ.z_excl, divide, store.
// All LDS tiles XOR-swizzled: idx ^= (row&7)<<3  (kills 16-way stride-128B/256B
// bank conflicts on every ds_read_b128 fragment read).

#define BH 8
#define D 64
#define DV 64
#define NSEQ 2048
#define M 128
#define CHK 64
#define NC (NSEQ / CHK)
#define PHI_SCALE 0.08838834764831845f  // 1/sqrt(128)

typedef unsigned int uint;
typedef unsigned short ushort;
typedef __attribute__((ext_vector_type(8))) short bf16x8;
typedef __attribute__((ext_vector_type(4))) short bf16x4;
typedef __attribute__((ext_vector_type(4))) float f32x4;
#define MFMA16(a, b, c) __builtin_amdgcn_mfma_f32_16x16x32_bf16((a), (b), (c), 0, 0, 0)

__device__ __forceinline__ short f2bf(float x) {  // RNE truncate fp32->bf16
    uint u = __float_as_uint(x);
    u += 0x7fffu + ((u >> 16) & 1u);
    return (short)(u >> 16);
}
__device__ __forceinline__ float bf2f(short b) {
    return __uint_as_float(((uint)(ushort)b) << 16);
}

// element-index XOR swizzles for bf16 tiles (rows of 64 / 128 elements)
#define SWZ64(r, c)  ((r) * 64  + ((c) ^ (((r) & 7) << 3)))
#define SWZ128(r, c) ((r) * 128 + ((c) ^ (((r) & 7) << 3)))

__global__ __launch_bounds__(256) void favor_fused(
    const float* __restrict__ keys, const float* __restrict__ values,
    const float* __restrict__ queries, const float* __restrict__ features,
    ushort* __restrict__ St, float* __restrict__ z, float* __restrict__ out)
{
    const int bh = blockIdx.x >> 5, c = blockIdx.x & 31, n0 = c * CHK;
    const int tid = threadIdx.x;
    const int lane = tid & 63, wid = tid >> 6, quad = lane >> 4, l16 = lane & 15;

    __shared__ ulong2 smv[5168];                     // 82688 B -> 1 block/CU
    short* sF    = (short*)smv;                      // [128][64] bf16 F (phase A)
    short* sPKmn = (short*)smv + 8192;               // [128][64] bf16 phiK[m][n]
    short* sPQt  = (short*)smv + 16384;              // [64][128] bf16 phiQ^T (A->C)
    short* sPKt  = (short*)smv + 24576;              // [64][128] bf16 phiK^T
    short* sAm   = (short*)smv + 32768;              // [64][64]  bf16 Amat
    short* sV    = (short*)smv + 36864;              // [64][64]  bf16 V[v][n]
    float* sNm   = (float*)((char*)smv + 81920);     // [64] norm
    float* sZ    = (float*)((char*)smv + 82176);     // [128] z_excl
    float* sOut  = (float*)smv;                      // [64][65] f32 (phase C, alias sF)

    // ---------------- Phase A ----------------
    // early-issue all global loads (K,Q,V) so latency hides under F staging
    const float* Kb = keys    + bh * D * NSEQ + n0 + 16 * wid + l16;
    const float* Qb = queries + bh * D * NSEQ + n0 + 16 * wid + l16;
    bf16x8 bK[2], aQ[2], aV[2];
    for (int h = 0; h < 2; ++h)
        for (int j = 0; j < 8; ++j) {
            const int d = 32 * h + 8 * quad + j;
            bK[h][j] = f2bf(Kb[d * NSEQ]);   // B-frag for phiK[m][n], A-frag for phiK^T
            aQ[h][j] = f2bf(Qb[d * NSEQ]);   // A-frag for phiQ^T
        }
    {
        const float* Vb = values + bh * DV * NSEQ + n0;
        for (int h = 0; h < 2; ++h) {
            const float4* vp = (const float4*)(Vb + (16 * wid + l16) * NSEQ + 32 * h + 8 * quad);
            float4 v0 = vp[0], v1 = vp[1];
            aV[h][0] = f2bf(v0.x); aV[h][1] = f2bf(v0.y);
            aV[h][2] = f2bf(v0.z); aV[h][3] = f2bf(v0.w);
            aV[h][4] = f2bf(v1.x); aV[h][5] = f2bf(v1.y);
            aV[h][6] = f2bf(v1.z); aV[h][7] = f2bf(v1.w);
        }
        // stage V tile straight from the frags (row v = 16wid+l16)
        for (int h = 0; h < 2; ++h)
            *(bf16x8*)(sV + SWZ64(16 * wid + l16, 32 * h + 8 * quad)) = aV[h];
    }
    // stage F fp32->bf16, vectorized float4 -> 8B ds_write
    for (int k = 0; k < 8; ++k) {
        const int i = tid + 256 * k;                 // float4 index, 2048 total
        float4 f = ((const float4*)features)[i];
        const int e = 4 * i, row = e >> 6, col = e & 63;
        bf16x4 bq;
        bq[0] = f2bf(f.x); bq[1] = f2bf(f.y); bq[2] = f2bf(f.z); bq[3] = f2bf(f.w);
        *(bf16x4*)(sF + SWZ64(row, col)) = bq;
    }
    __syncthreads();  // B1: sF, sV ready

    // phi generation: one sF read feeds 3 MFMAs (phiK[m][n], phiQ^T, phiK^T)
    for (int mt = 0; mt < 8; ++mt) {
        f32x4 aMN = {0.f,0.f,0.f,0.f}, aQm = {0.f,0.f,0.f,0.f}, aKm = {0.f,0.f,0.f,0.f};
        for (int h = 0; h < 2; ++h) {
            bf16x8 fF = *(const bf16x8*)(sF + SWZ64(16 * mt + l16, 32 * h + 8 * quad));
            aMN = MFMA16(fF, bK[h], aMN);     // D[m][n] = F . K
            aQm = MFMA16(aQ[h], fF, aQm);     // D[n][m] = Q^T . F^T
            aKm = MFMA16(bK[h], fF, aKm);     // D[n][m] = K^T . F^T
        }
        for (int r = 0; r < 4; ++r) {
            const int mr = 16 * mt + 4 * quad + r;       // row m
            sPKmn[SWZ64(mr, 16 * wid + l16)] = f2bf(fmaxf(aMN[r], 0.f) * PHI_SCALE);
            const int nr = 16 * wid + 4 * quad + r;      // row n
            sPQt[SWZ128(nr, 16 * mt + l16)] = f2bf(fmaxf(aQm[r], 0.f) * PHI_SCALE);
            sPKt[SWZ128(nr, 16 * mt + l16)] = f2bf(fmaxf(aKm[r], 0.f) * PHI_SCALE);
        }
    }
    __syncthreads();  // B2: phi tiles ready

    // z[m] = sum_n phiK[m][n]  (chunk-local, scanned in phase B)
    if (tid < 128) {
        float s = 0.f;
        for (int n = 0; n < 64; ++n) s += bf2f(sPKmn[SWZ64(tid, (n + tid) & 63)]);
        z[(bh * NC + c) * M + tid] = s;
    }

    // S^T[v][m] chunk-local -> global St
    {
        ushort* So = St + (size_t)(bh * NC + c) * (DV * M);
        for (int mt = 0; mt < 8; ++mt) {
            f32x4 acc = {0.f,0.f,0.f,0.f};
            for (int h = 0; h < 2; ++h) {
                bf16x8 bP = *(const bf16x8*)(sPKmn + SWZ64(16 * mt + l16, 32 * h + 8 * quad));
                acc = MFMA16(aV[h], bP, acc);
            }
            for (int r = 0; r < 4; ++r)
                So[(16 * wid + 4 * quad + r) * M + 16 * mt + l16] = (ushort)f2bf(acc[r]);
        }
    }

    // C: Amat[n][j] = phiQ^T . phiK (masked), row-sums -> intra norm
    f32x4 accO[4], accC[4];
    for (int t = 0; t < 4; ++t) { accO[t] = (f32x4){0.f,0.f,0.f,0.f}; accC[t] = (f32x4){0.f,0.f,0.f,0.f}; }
    for (int mt = 0; mt < 4; ++mt) {
        bf16x8 aP = *(const bf16x8*)(sPQt + SWZ128(16 * wid + l16, 32 * mt + 8 * quad));
        for (int jt = 0; jt < 4; ++jt) {
            bf16x8 bK2 = *(const bf16x8*)(sPKt + SWZ128(16 * jt + l16, 32 * mt + 8 * quad));
            accC[jt] = MFMA16(aP, bK2, accC[jt]);
        }
    }
    float rsum[4] = {0.f, 0.f, 0.f, 0.f};
    for (int jt = 0; jt < 4; ++jt)
        for (int r = 0; r < 4; ++r) {
            const int n = 16 * wid + 4 * quad + r;
            const int j = 16 * jt + l16;
            const float av = (j <= n) ? accC[jt][r] : 0.f;
            rsum[r] += av;
            sAm[SWZ64(n, j)] = f2bf(av);
        }
    for (int r = 0; r < 4; ++r) {
        float s = rsum[r];
        s += __shfl_xor(s, 1); s += __shfl_xor(s, 2);
        s += __shfl_xor(s, 4); s += __shfl_xor(s, 8);
        if (l16 == 0) sNm[16 * wid + 4 * quad + r] = s;  // intra part of norm
    }
    __syncthreads();  // B3: sAm ready

    // E: accO += Amat . V   (intra-chunk causal contribution)
    for (int jh = 0; jh < 2; ++jh) {
        bf16x8 aA = *(const bf16x8*)(sAm + SWZ64(16 * wid + l16, 32 * jh + 8 * quad));
        for (int vt = 0; vt < 4; ++vt) {
            bf16x8 bV = *(const bf16x8*)(sV + SWZ64(16 * vt + l16, 32 * jh + 8 * quad));
            accO[vt] = MFMA16(aA, bV, accO[vt]);
        }
    }

    cg::this_grid().sync();  // GS1: all chunk-local St / z visible

    // ---------------- Phase B: exclusive prefix scans over chunks ----------------
    {
        const int gid = blockIdx.x * 256 + tid;          // 65536 S^T columns
        const int sbh = gid >> 13, vm = gid & 8191;
        ushort* p = St + (size_t)sbh * NC * 8192 + vm;
        float vals[NC];
        #pragma unroll
        for (int cc = 0; cc < NC; ++cc) vals[cc] = bf2f(p[cc * 8192]);
        float run = 0.f;
        #pragma unroll
        for (int cc = 0; cc < NC; ++cc) { p[cc * 8192] = (ushort)f2bf(run); run += vals[cc]; }
        if (blockIdx.x < 4) {                            // 1024 z columns
            const int i = blockIdx.x * 256 + tid;
            const int zbh = i >> 7, m = i & 127;
            float* zp = z + zbh * NC * M + m;
            #pragma unroll
            for (int cc = 0; cc < NC; ++cc) vals[cc] = zp[cc * M];
            float zr = 0.f;
            #pragma unroll
            for (int cc = 0; cc < NC; ++cc) { zp[cc * M] = zr; zr += vals[cc]; }
        }
    }

    cg::this_grid().sync();  // GS2: scanned St / z visible

    // ---------------- Phase C ----------------
    if (tid < 128) sZ[tid] = z[(bh * NC + c) * M + tid];
    {
        const ushort* Sb = St + (size_t)(bh * NC + c) * (DV * M);
        for (int mt = 0; mt < 4; ++mt) {
            bf16x8 aP = *(const bf16x8*)(sPQt + SWZ128(16 * wid + l16, 32 * mt + 8 * quad));
            for (int vt = 0; vt < 4; ++vt) {
                bf16x8 bS = *(const bf16x8*)(Sb + (16 * vt + l16) * M + 32 * mt + 8 * quad);
                accO[vt] = MFMA16(aP, bS, accO[vt]);     // accO += phiQ . S_excl
            }
        }
    }
    __syncthreads();  // B5: sZ staged
    if (tid < 64) {   // inter part of norm: phiQ[n] . z_excl
        float s = 0.f;
        for (int mm = 0; mm < 128; ++mm) {
            const int m = (mm + 2 * tid) & 127;          // rotate: spread banks
            s += bf2f(sPQt[SWZ128(tid, m)]) * sZ[m];
        }
        sNm[tid] += s;
    }
    __syncthreads();  // B6: sNm final
    for (int vt = 0; vt < 4; ++vt)
        for (int r = 0; r < 4; ++r) {
            const int n = 16 * wid + 4 * quad + r, v = 16 * vt + l16;
            sOut[n * 65 + v] = accO[vt][r] / sNm[n];
        }
    __syncthreads();  // B7
    for (int i = tid; i < 4096; i += 256) {
        const int v = i >> 6, n = i & 63;
        out[(bh * DV + v) * NSEQ + n0 + n] = sOut[n * 65 + v];
    }
}

extern "C" void kernel_launch(void* const* d_in, const int* in_sizes, int n_in,
                              void* d_out, int out_size, void* d_ws, size_t ws_size,
                              hipStream_t stream)
{
    (void)in_sizes; (void)n_in; (void)out_size; (void)ws_size;
    const float* keys     = (const float*)d_in[0];
    const float* values   = (const float*)d_in[1];
    const float* queries  = (const float*)d_in[2];
    const float* features = (const float*)d_in[3];
    float* outp = (float*)d_out;

    // ws: S^T bf16 [BH][NC][DV][M] (4 MB) then z fp32 [BH][NC][M] (128 KB)
    ushort* St = (ushort*)d_ws;
    float*  z  = (float*)((char*)d_ws + (size_t)BH * NC * DV * M * sizeof(ushort));

    void* args[] = {(void*)&keys, (void*)&values, (void*)&queries, (void*)&features,
                    (void*)&St, (void*)&z, (void*)&outp};
    hipLaunchCooperativeKernel(reinterpret_cast<const void*>(&favor_fused),
                               dim3(BH * NC), dim3(256), args, 0u, stream);
}

// Round 3
// 99.334 us; speedup vs baseline: 1.4753x; 1.4753x over previous
//
#include <hip/hip_runtime.h>

// FAVOR+ causal linear attention — 2-kernel chunk-parallel pipeline.
// BH=8, D=DV=64, N=2048, M=128, chunk C=64, NC=32; 256 blocks x 256 thr each.
//
// K1 (per chunk): phi-gen (3 orientations from one F-frag read), writes
//   chunk-local S^T (bf16) + z (f32) + swizzled phiQ^T / phiK^T LDS images
//   to global (coalesced).
// K2 (per chunk): reload phi images (coalesced 16B/lane), fold the prefix
//   scan in: sum c predecessor S^T chunks (fp32 regs) + z prefix, then
//   intra-causal GEMM + inter GEMM + norm + store.  No grid sync, no
//   cooperative launch, no scan dispatch, no phi recompute.
// All LDS tiles XOR-swizzled: col ^= (row&7)<<3 (8-element granularity safe).

#define BH 8
#define D 64
#define DV 64
#define NSEQ 2048
#define M 128
#define CHK 64
#define NC (NSEQ / CHK)
#define PHI_SCALE 0.08838834764831845f  // 1/sqrt(128)

typedef unsigned int uint;
typedef unsigned short ushort;
typedef __attribute__((ext_vector_type(8))) short bf16x8;
typedef __attribute__((ext_vector_type(4))) short bf16x4;
typedef __attribute__((ext_vector_type(4))) float f32x4;
#define MFMA16(a, b, c) __builtin_amdgcn_mfma_f32_16x16x32_bf16((a), (b), (c), 0, 0, 0)

__device__ __forceinline__ short f2bf(float x) {  // RNE truncate fp32->bf16
    uint u = __float_as_uint(x);
    u += 0x7fffu + ((u >> 16) & 1u);
    return (short)(u >> 16);
}
__device__ __forceinline__ float bf2f(short b) {
    return __uint_as_float(((uint)(ushort)b) << 16);
}

// element-index XOR swizzles for bf16 tiles (rows of 64 / 128 elements)
#define SWZ64(r, c)  ((r) * 64  + ((c) ^ (((r) & 7) << 3)))
#define SWZ128(r, c) ((r) * 128 + ((c) ^ (((r) & 7) << 3)))

// ---------------- Kernel 1 ----------------
__global__ __launch_bounds__(256) void favor_p1(
    const float* __restrict__ keys, const float* __restrict__ values,
    const float* __restrict__ queries, const float* __restrict__ features,
    ushort* __restrict__ St, float* __restrict__ z,
    ushort* __restrict__ pQg, ushort* __restrict__ pKg)
{
    const int bh = blockIdx.x >> 5, c = blockIdx.x & 31, n0 = c * CHK;
    const int tid = threadIdx.x;
    const int lane = tid & 63, wid = tid >> 6, quad = lane >> 4, l16 = lane & 15;

    __shared__ ulong2 smv[4096];               // 64 KB
    short* sF    = (short*)smv;                // [128][64] bf16 F
    short* sPKmn = (short*)smv + 8192;         // [128][64] bf16 phiK[m][n]
    short* sPQt  = (short*)smv + 16384;        // [64][128] bf16 phiQ^T
    short* sPKt  = (short*)smv + 24576;        // [64][128] bf16 phiK^T

    // early-issue all global loads (K,Q,V) so latency hides under F staging
    const float* Kb = keys    + bh * D * NSEQ + n0 + 16 * wid + l16;
    const float* Qb = queries + bh * D * NSEQ + n0 + 16 * wid + l16;
    bf16x8 bK[2], aQ[2], aV[2];
    for (int h = 0; h < 2; ++h)
        for (int j = 0; j < 8; ++j) {
            const int d = 32 * h + 8 * quad + j;
            bK[h][j] = f2bf(Kb[d * NSEQ]);     // B-frag phiK[m][n], A-frag phiK^T
            aQ[h][j] = f2bf(Qb[d * NSEQ]);     // A-frag phiQ^T
        }
    {
        const float* Vb = values + bh * DV * NSEQ + n0;
        for (int h = 0; h < 2; ++h) {
            const float4* vp = (const float4*)(Vb + (16 * wid + l16) * NSEQ + 32 * h + 8 * quad);
            float4 v0 = vp[0], v1 = vp[1];
            aV[h][0] = f2bf(v0.x); aV[h][1] = f2bf(v0.y);
            aV[h][2] = f2bf(v0.z); aV[h][3] = f2bf(v0.w);
            aV[h][4] = f2bf(v1.x); aV[h][5] = f2bf(v1.y);
            aV[h][6] = f2bf(v1.z); aV[h][7] = f2bf(v1.w);
        }
    }
    // stage F fp32->bf16, vectorized float4 -> 8B ds_write
    for (int k = 0; k < 8; ++k) {
        const int i = tid + 256 * k;           // float4 index, 2048 total
        float4 f = ((const float4*)features)[i];
        const int e = 4 * i, row = e >> 6, col = e & 63;
        bf16x4 bq;
        bq[0] = f2bf(f.x); bq[1] = f2bf(f.y); bq[2] = f2bf(f.z); bq[3] = f2bf(f.w);
        *(bf16x4*)(sF + SWZ64(row, col)) = bq;
    }
    __syncthreads();  // B1: sF ready

    // phi generation: one sF read feeds 3 MFMAs
    for (int mt = 0; mt < 8; ++mt) {
        f32x4 aMN = {0.f,0.f,0.f,0.f}, aQm = {0.f,0.f,0.f,0.f}, aKm = {0.f,0.f,0.f,0.f};
        for (int h = 0; h < 2; ++h) {
            bf16x8 fF = *(const bf16x8*)(sF + SWZ64(16 * mt + l16, 32 * h + 8 * quad));
            aMN = MFMA16(fF, bK[h], aMN);      // D[m][n] = F . K
            aQm = MFMA16(aQ[h], fF, aQm);      // D[n][m] = Q^T . F^T
            aKm = MFMA16(bK[h], fF, aKm);      // D[n][m] = K^T . F^T
        }
        for (int r = 0; r < 4; ++r) {
            const int mr = 16 * mt + 4 * quad + r;     // row m
            sPKmn[SWZ64(mr, 16 * wid + l16)] = f2bf(fmaxf(aMN[r], 0.f) * PHI_SCALE);
            const int nr = 16 * wid + 4 * quad + r;    // row n
            sPQt[SWZ128(nr, 16 * mt + l16)] = f2bf(fmaxf(aQm[r], 0.f) * PHI_SCALE);
            sPKt[SWZ128(nr, 16 * mt + l16)] = f2bf(fmaxf(aKm[r], 0.f) * PHI_SCALE);
        }
    }
    __syncthreads();  // B2: phi tiles ready

    // z[m] = sum_n phiK[m][n]  (chunk-local; K2 does the prefix)
    if (tid < 128) {
        float s = 0.f;
        for (int k = 0; k < 8; ++k) {
            bf16x8 v8 = *(const bf16x8*)(sPKmn + SWZ64(tid, 8 * k));
            for (int j = 0; j < 8; ++j) s += bf2f(v8[j]);
        }
        z[(bh * NC + c) * M + tid] = s;
    }

    // S^T[v][m] chunk-local -> global St
    {
        ushort* So = St + (size_t)(bh * NC + c) * (DV * M);
        for (int mt = 0; mt < 8; ++mt) {
            f32x4 acc = {0.f,0.f,0.f,0.f};
            for (int h = 0; h < 2; ++h) {
                bf16x8 bP = *(const bf16x8*)(sPKmn + SWZ64(16 * mt + l16, 32 * h + 8 * quad));
                acc = MFMA16(aV[h], bP, acc);
            }
            for (int r = 0; r < 4; ++r)
                So[(16 * wid + 4 * quad + r) * M + 16 * mt + l16] = (ushort)f2bf(acc[r]);
        }
    }

    // phi images (swizzled LDS layout) -> global, fully coalesced 16B/lane
    {
        ushort* pQc = pQg + (size_t)(bh * NC + c) * 8192;
        ushort* pKc = pKg + (size_t)(bh * NC + c) * 8192;
        const ulong2* sq = (const ulong2*)sPQt;
        const ulong2* sk = (const ulong2*)sPKt;
        for (int i = tid; i < 1024; i += 256) {
            ((ulong2*)pQc)[i] = sq[i];
            ((ulong2*)pKc)[i] = sk[i];
        }
    }
}

// ---------------- Kernel 2 ----------------
__global__ __launch_bounds__(256) void favor_p2k(
    const float* __restrict__ values, const ushort* __restrict__ St,
    const float* __restrict__ z, const ushort* __restrict__ pQg,
    const ushort* __restrict__ pKg, float* __restrict__ out)
{
    const int bh = blockIdx.x >> 5, c = blockIdx.x & 31, n0 = c * CHK;
    const int tid = threadIdx.x;
    const int lane = tid & 63, wid = tid >> 6, quad = lane >> 4, l16 = lane & 15;

    __shared__ ulong2 smv[4144];                    // 66304 B
    short* sPQt = (short*)smv;                      // [64][128] bf16 phiQ^T
    short* sPKt = (short*)smv + 8192;               // [64][128] bf16 phiK^T
    short* sSx  = (short*)smv + 16384;              // [64][128] bf16 S_excl
    short* sV   = (short*)smv + 24576;              // [64][64]  bf16 V
    short* sAm  = (short*)smv + 28672;              // [64][64]  bf16 Amat
    float* sNm  = (float*)((char*)smv + 65536);     // [64] norm
    float* sZ   = (float*)((char*)smv + 65792);     // [128] z_excl
    float* sOut = (float*)((char*)smv + 32768);     // [64][65] f32 (aliases sSx+sV head, dead by then)

    // phi images global->LDS (coalesced 16B/lane; swizzle already baked in)
    {
        const ulong2* pQc = (const ulong2*)(pQg + (size_t)(bh * NC + c) * 8192);
        const ulong2* pKc = (const ulong2*)(pKg + (size_t)(bh * NC + c) * 8192);
        ulong2* dq = (ulong2*)sPQt;
        ulong2* dk = (ulong2*)sPKt;
        for (int i = tid; i < 1024; i += 256) {
            dq[i] = pQc[i];
            dk[i] = pKc[i];
        }
    }

    // V stage: thread -> row v = tid>>2, 16 cols
    {
        const int v = tid >> 2, cb = (tid & 3) * 16;
        const float4* vp = (const float4*)(values + (bh * DV + v) * NSEQ + n0 + cb);
        float4 f0 = vp[0], f1 = vp[1], f2 = vp[2], f3 = vp[3];
        bf16x8 lo, hi;
        lo[0] = f2bf(f0.x); lo[1] = f2bf(f0.y); lo[2] = f2bf(f0.z); lo[3] = f2bf(f0.w);
        lo[4] = f2bf(f1.x); lo[5] = f2bf(f1.y); lo[6] = f2bf(f1.z); lo[7] = f2bf(f1.w);
        hi[0] = f2bf(f2.x); hi[1] = f2bf(f2.y); hi[2] = f2bf(f2.z); hi[3] = f2bf(f2.w);
        hi[4] = f2bf(f3.x); hi[5] = f2bf(f3.y); hi[6] = f2bf(f3.z); hi[7] = f2bf(f3.w);
        *(bf16x8*)(sV + SWZ64(v, cb))     = lo;
        *(bf16x8*)(sV + SWZ64(v, cb + 8)) = hi;
    }

    // z exclusive prefix (fp32 sum of predecessors)
    if (tid < 128) {
        float s = 0.f;
        const float* zp = z + bh * NC * M + tid;
        #pragma unroll 4
        for (int cc = 0; cc < c; ++cc) s += zp[cc * M];
        sZ[tid] = s;
    }

    // S_excl = sum of predecessor chunk S^T's, fp32 accum -> bf16 swizzled LDS
    {
        float a32[4][8];
        #pragma unroll
        for (int k = 0; k < 4; ++k)
            #pragma unroll
            for (int j = 0; j < 8; ++j) a32[k][j] = 0.f;
        const ushort* Sb = St + (size_t)bh * NC * 8192;
        for (int cc = 0; cc < c; ++cc) {
            const ushort* p = Sb + (size_t)cc * 8192;
            #pragma unroll
            for (int k = 0; k < 4; ++k) {
                bf16x8 v8 = *(const bf16x8*)(p + 8 * (tid + 256 * k));
                #pragma unroll
                for (int j = 0; j < 8; ++j) a32[k][j] += bf2f(v8[j]);
            }
        }
        #pragma unroll
        for (int k = 0; k < 4; ++k) {
            const int e = tid + 256 * k;            // bf16x8 group index
            bf16x8 w;
            #pragma unroll
            for (int j = 0; j < 8; ++j) w[j] = f2bf(a32[k][j]);
            *(bf16x8*)(sSx + SWZ128(e >> 4, 8 * (e & 15))) = w;
        }
    }
    __syncthreads();  // B1: sPQt, sPKt, sSx, sV, sZ staged

    // C: Amat[n][j] = phiQ^T . phiK (masked), row-sums -> intra norm
    f32x4 accO[4], accC[4];
    for (int t = 0; t < 4; ++t) { accO[t] = (f32x4){0.f,0.f,0.f,0.f}; accC[t] = (f32x4){0.f,0.f,0.f,0.f}; }
    for (int mt = 0; mt < 4; ++mt) {
        bf16x8 aP = *(const bf16x8*)(sPQt + SWZ128(16 * wid + l16, 32 * mt + 8 * quad));
        for (int jt = 0; jt < 4; ++jt) {
            bf16x8 bK2 = *(const bf16x8*)(sPKt + SWZ128(16 * jt + l16, 32 * mt + 8 * quad));
            accC[jt] = MFMA16(aP, bK2, accC[jt]);
        }
    }
    float rsum[4] = {0.f, 0.f, 0.f, 0.f};
    for (int jt = 0; jt < 4; ++jt)
        for (int r = 0; r < 4; ++r) {
            const int n = 16 * wid + 4 * quad + r;
            const int j = 16 * jt + l16;
            const float av = (j <= n) ? accC[jt][r] : 0.f;
            rsum[r] += av;
            sAm[SWZ64(n, j)] = f2bf(av);
        }
    for (int r = 0; r < 4; ++r) {
        float s = rsum[r];
        s += __shfl_xor(s, 1); s += __shfl_xor(s, 2);
        s += __shfl_xor(s, 4); s += __shfl_xor(s, 8);
        if (l16 == 0) sNm[16 * wid + 4 * quad + r] = s;  // intra part of norm
    }
    __syncthreads();  // B2: sAm, sNm(intra) ready

    // E: accO += Amat . V   (intra-chunk causal)
    for (int jh = 0; jh < 2; ++jh) {
        bf16x8 aA = *(const bf16x8*)(sAm + SWZ64(16 * wid + l16, 32 * jh + 8 * quad));
        for (int vt = 0; vt < 4; ++vt) {
            bf16x8 bV = *(const bf16x8*)(sV + SWZ64(16 * vt + l16, 32 * jh + 8 * quad));
            accO[vt] = MFMA16(aA, bV, accO[vt]);
        }
    }
    // inter: accO += phiQ^T . S_excl
    for (int mt = 0; mt < 4; ++mt) {
        bf16x8 aP = *(const bf16x8*)(sPQt + SWZ128(16 * wid + l16, 32 * mt + 8 * quad));
        for (int vt = 0; vt < 4; ++vt) {
            bf16x8 bS = *(const bf16x8*)(sSx + SWZ128(16 * vt + l16, 32 * mt + 8 * quad));
            accO[vt] = MFMA16(aP, bS, accO[vt]);
        }
    }
    // norm inter part: phiQ[n] . z_excl
    if (tid < 64) {
        float s = 0.f;
        for (int mm = 0; mm < 128; ++mm) {
            const int m = (mm + 2 * tid) & 127;          // rotate: spread banks
            s += bf2f(sPQt[SWZ128(tid, m)]) * sZ[m];
        }
        sNm[tid] += s;
    }
    __syncthreads();  // B3: sNm final; sSx/sV dead -> sOut alias safe

    for (int vt = 0; vt < 4; ++vt)
        for (int r = 0; r < 4; ++r) {
            const int n = 16 * wid + 4 * quad + r, v = 16 * vt + l16;
            sOut[n * 65 + v] = accO[vt][r] / sNm[n];
        }
    __syncthreads();  // B4
    for (int i = tid; i < 4096; i += 256) {
        const int v = i >> 6, n = i & 63;
        out[(bh * DV + v) * NSEQ + n0 + n] = sOut[n * 65 + v];
    }
}

extern "C" void kernel_launch(void* const* d_in, const int* in_sizes, int n_in,
                              void* d_out, int out_size, void* d_ws, size_t ws_size,
                              hipStream_t stream)
{
    (void)in_sizes; (void)n_in; (void)out_size; (void)ws_size;
    const float* keys     = (const float*)d_in[0];
    const float* values   = (const float*)d_in[1];
    const float* queries  = (const float*)d_in[2];
    const float* features = (const float*)d_in[3];
    float* outp = (float*)d_out;

    // ws: St bf16 [BH][NC][DV][M] (4 MB) | z f32 [BH][NC][M] (128 KB)
    //   | pQ bf16 images (4 MB) | pK bf16 images (4 MB)   (ws is 256 MB)
    char* w = (char*)d_ws;
    ushort* St  = (ushort*)w;
    float*  z   = (float*)(w + (size_t)4 * 1024 * 1024);
    ushort* pQg = (ushort*)(w + (size_t)4 * 1024 * 1024 + 128 * 1024);
    ushort* pKg = (ushort*)(w + (size_t)8 * 1024 * 1024 + 128 * 1024);

    favor_p1<<<dim3(BH * NC), dim3(256), 0, stream>>>(keys, values, queries, features,
                                                      St, z, pQg, pKg);
    favor_p2k<<<dim3(BH * NC), dim3(256), 0, stream>>>(values, St, z, pQg, pKg, outp);
}

// Round 4
// 89.253 us; speedup vs baseline: 1.6420x; 1.1129x over previous
//
#include <hip/hip_runtime.h>

// FAVOR+ causal linear attention — 3-kernel chunk-parallel pipeline.
// BH=8, D=DV=64, N=2048, M=128, chunk C=64, NC=32; 256 blocks x 256 thr.
//
// K1 (per chunk): phi-gen (3 orientations from one F-frag read), writes
//   chunk-local S^T (bf16) + z (f32) + swizzled phiQ^T/phiK^T LDS images.
// K2: massively parallel exclusive prefix scan over chunks (St bf16, z f32)
//   — 65536 threads, one column element each (no per-block serial chunk sum).
// K3 (per chunk): reload phi images (coalesced 16B/lane, no F/Q/K reload,
//   no phi recompute), intra-causal GEMM + inter GEMM (S_excl B-frags direct
//   from global) + parallel norm + store.
// All LDS tiles XOR-swizzled: col ^= (row&7)<<3.

#define BH 8
#define D 64
#define DV 64
#define NSEQ 2048
#define M 128
#define CHK 64
#define NC (NSEQ / CHK)
#define PHI_SCALE 0.08838834764831845f  // 1/sqrt(128)

typedef unsigned int uint;
typedef unsigned short ushort;
typedef __attribute__((ext_vector_type(8))) short bf16x8;
typedef __attribute__((ext_vector_type(4))) short bf16x4;
typedef __attribute__((ext_vector_type(4))) float f32x4;
#define MFMA16(a, b, c) __builtin_amdgcn_mfma_f32_16x16x32_bf16((a), (b), (c), 0, 0, 0)

__device__ __forceinline__ short f2bf(float x) {  // RNE truncate fp32->bf16
    uint u = __float_as_uint(x);
    u += 0x7fffu + ((u >> 16) & 1u);
    return (short)(u >> 16);
}
__device__ __forceinline__ float bf2f(short b) {
    return __uint_as_float(((uint)(ushort)b) << 16);
}

// element-index XOR swizzles for bf16 tiles (rows of 64 / 128 elements)
#define SWZ64(r, c)  ((r) * 64  + ((c) ^ (((r) & 7) << 3)))
#define SWZ128(r, c) ((r) * 128 + ((c) ^ (((r) & 7) << 3)))

// ---------------- Kernel 1 ----------------
__global__ __launch_bounds__(256) void favor_p1(
    const float* __restrict__ keys, const float* __restrict__ values,
    const float* __restrict__ queries, const float* __restrict__ features,
    ushort* __restrict__ St, float* __restrict__ z,
    ushort* __restrict__ pQg, ushort* __restrict__ pKg)
{
    const int bh = blockIdx.x >> 5, c = blockIdx.x & 31, n0 = c * CHK;
    const int tid = threadIdx.x;
    const int lane = tid & 63, wid = tid >> 6, quad = lane >> 4, l16 = lane & 15;

    __shared__ ulong2 smv[4096];               // 64 KB
    short* sF    = (short*)smv;                // [128][64] bf16 F
    short* sPKmn = (short*)smv + 8192;         // [128][64] bf16 phiK[m][n]
    short* sPQt  = (short*)smv + 16384;        // [64][128] bf16 phiQ^T
    short* sPKt  = (short*)smv + 24576;        // [64][128] bf16 phiK^T

    // early-issue all global loads (K,Q,V) so latency hides under F staging
    const float* Kb = keys    + bh * D * NSEQ + n0 + 16 * wid + l16;
    const float* Qb = queries + bh * D * NSEQ + n0 + 16 * wid + l16;
    bf16x8 bK[2], aQ[2], aV[2];
    for (int h = 0; h < 2; ++h)
        for (int j = 0; j < 8; ++j) {
            const int d = 32 * h + 8 * quad + j;
            bK[h][j] = f2bf(Kb[d * NSEQ]);     // B-frag phiK[m][n], A-frag phiK^T
            aQ[h][j] = f2bf(Qb[d * NSEQ]);     // A-frag phiQ^T
        }
    {
        const float* Vb = values + bh * DV * NSEQ + n0;
        for (int h = 0; h < 2; ++h) {
            const float4* vp = (const float4*)(Vb + (16 * wid + l16) * NSEQ + 32 * h + 8 * quad);
            float4 v0 = vp[0], v1 = vp[1];
            aV[h][0] = f2bf(v0.x); aV[h][1] = f2bf(v0.y);
            aV[h][2] = f2bf(v0.z); aV[h][3] = f2bf(v0.w);
            aV[h][4] = f2bf(v1.x); aV[h][5] = f2bf(v1.y);
            aV[h][6] = f2bf(v1.z); aV[h][7] = f2bf(v1.w);
        }
    }
    // stage F fp32->bf16, vectorized float4 -> 8B ds_write
    for (int k = 0; k < 8; ++k) {
        const int i = tid + 256 * k;           // float4 index, 2048 total
        float4 f = ((const float4*)features)[i];
        const int e = 4 * i, row = e >> 6, col = e & 63;
        bf16x4 bq;
        bq[0] = f2bf(f.x); bq[1] = f2bf(f.y); bq[2] = f2bf(f.z); bq[3] = f2bf(f.w);
        *(bf16x4*)(sF + SWZ64(row, col)) = bq;
    }
    __syncthreads();  // B1: sF ready

    // phi generation: one sF read feeds 3 MFMAs
    for (int mt = 0; mt < 8; ++mt) {
        f32x4 aMN = {0.f,0.f,0.f,0.f}, aQm = {0.f,0.f,0.f,0.f}, aKm = {0.f,0.f,0.f,0.f};
        for (int h = 0; h < 2; ++h) {
            bf16x8 fF = *(const bf16x8*)(sF + SWZ64(16 * mt + l16, 32 * h + 8 * quad));
            aMN = MFMA16(fF, bK[h], aMN);      // D[m][n] = F . K
            aQm = MFMA16(aQ[h], fF, aQm);      // D[n][m] = Q^T . F^T
            aKm = MFMA16(bK[h], fF, aKm);      // D[n][m] = K^T . F^T
        }
        for (int r = 0; r < 4; ++r) {
            const int mr = 16 * mt + 4 * quad + r;     // row m
            sPKmn[SWZ64(mr, 16 * wid + l16)] = f2bf(fmaxf(aMN[r], 0.f) * PHI_SCALE);
            const int nr = 16 * wid + 4 * quad + r;    // row n
            sPQt[SWZ128(nr, 16 * mt + l16)] = f2bf(fmaxf(aQm[r], 0.f) * PHI_SCALE);
            sPKt[SWZ128(nr, 16 * mt + l16)] = f2bf(fmaxf(aKm[r], 0.f) * PHI_SCALE);
        }
    }
    __syncthreads();  // B2: phi tiles ready

    // z[m] = sum_n phiK[m][n]  (chunk-local; K2 does the prefix)
    if (tid < 128) {
        float s = 0.f;
        for (int k = 0; k < 8; ++k) {
            bf16x8 v8 = *(const bf16x8*)(sPKmn + SWZ64(tid, 8 * k));
            for (int j = 0; j < 8; ++j) s += bf2f(v8[j]);
        }
        z[(bh * NC + c) * M + tid] = s;
    }

    // S^T[v][m] chunk-local -> global St
    {
        ushort* So = St + (size_t)(bh * NC + c) * (DV * M);
        for (int mt = 0; mt < 8; ++mt) {
            f32x4 acc = {0.f,0.f,0.f,0.f};
            for (int h = 0; h < 2; ++h) {
                bf16x8 bP = *(const bf16x8*)(sPKmn + SWZ64(16 * mt + l16, 32 * h + 8 * quad));
                acc = MFMA16(aV[h], bP, acc);
            }
            for (int r = 0; r < 4; ++r)
                So[(16 * wid + 4 * quad + r) * M + 16 * mt + l16] = (ushort)f2bf(acc[r]);
        }
    }

    // phi images (swizzled LDS layout) -> global, fully coalesced 16B/lane
    {
        ushort* pQc = pQg + (size_t)(bh * NC + c) * 8192;
        ushort* pKc = pKg + (size_t)(bh * NC + c) * 8192;
        const ulong2* sq = (const ulong2*)sPQt;
        const ulong2* sk = (const ulong2*)sPKt;
        for (int i = tid; i < 1024; i += 256) {
            ((ulong2*)pQc)[i] = sq[i];
            ((ulong2*)pKc)[i] = sk[i];
        }
    }
}

// ---------------- Kernel 2: exclusive prefix scans over chunks ----------------
// Massively parallel: 1 column element per thread, 32 strided loads then
// 32 strided stores (all independent -> one latency exposure, no imbalance).
__global__ __launch_bounds__(256) void favor_p2(ushort* __restrict__ St,
                                                float* __restrict__ z)
{
    const int gid = blockIdx.x * 256 + threadIdx.x;
    if (blockIdx.x < 256) {                       // S^T columns: 8*64*128 = 65536
        const int bh = gid >> 13, vm = gid & 8191;
        ushort* p = St + (size_t)bh * NC * 8192 + vm;
        float vals[NC];
        #pragma unroll
        for (int cc = 0; cc < NC; ++cc) vals[cc] = bf2f(p[cc * 8192]);
        float run = 0.f;
        #pragma unroll
        for (int cc = 0; cc < NC; ++cc) { p[cc * 8192] = (ushort)f2bf(run); run += vals[cc]; }
    } else {                                      // z columns: 8*128 = 1024
        const int i = gid - 65536;
        if (i < BH * M) {
            const int bh = i >> 7, m = i & 127;
            float* p = z + bh * NC * M + m;
            float vals[NC];
            #pragma unroll
            for (int cc = 0; cc < NC; ++cc) vals[cc] = p[cc * M];
            float run = 0.f;
            #pragma unroll
            for (int cc = 0; cc < NC; ++cc) { p[cc * M] = run; run += vals[cc]; }
        }
    }
}

// ---------------- Kernel 3 ----------------
__global__ __launch_bounds__(256) void favor_p3(
    const float* __restrict__ values, const ushort* __restrict__ St,
    const float* __restrict__ z, const ushort* __restrict__ pQg,
    const ushort* __restrict__ pKg, float* __restrict__ out)
{
    const int bh = blockIdx.x >> 5, c = blockIdx.x & 31, n0 = c * CHK;
    const int tid = threadIdx.x;
    const int lane = tid & 63, wid = tid >> 6, quad = lane >> 4, l16 = lane & 15;

    __shared__ ulong2 smv[3184];                    // 50944 B
    short* sPQt = (short*)smv;                      // [64][128] bf16 phiQ^T @0
    short* sPKt = (short*)smv + 8192;               // [64][128] bf16 phiK^T @16384
    short* sV   = (short*)smv + 16384;              // [64][64]  bf16 V      @32768
    short* sAm  = (short*)smv + 20480;              // [64][64]  bf16 Amat   @40960
    float* sNm  = (float*)((char*)smv + 49152);     // [64] norm
    float* sNmP = (float*)((char*)smv + 49408);     // [64][4] norm-inter partials
    float* sZ   = (float*)((char*)smv + 50432);     // [128] z_excl
    float* sOut = (float*)smv;                      // [64][65] f32 (16640B, aliases
                                                    //  sPQt/sPKt; all reads pre-B2)

    // phi images global->LDS (coalesced 16B/lane; swizzle already baked in)
    {
        const ulong2* pQc = (const ulong2*)(pQg + (size_t)(bh * NC + c) * 8192);
        const ulong2* pKc = (const ulong2*)(pKg + (size_t)(bh * NC + c) * 8192);
        ulong2* dq = (ulong2*)sPQt;
        ulong2* dk = (ulong2*)sPKt;
        for (int i = tid; i < 1024; i += 256) {
            dq[i] = pQc[i];
            dk[i] = pKc[i];
        }
    }
    // V stage: thread -> row v = tid>>2, 16 cols
    {
        const int v = tid >> 2, cb = (tid & 3) * 16;
        const float4* vp = (const float4*)(values + (bh * DV + v) * NSEQ + n0 + cb);
        float4 f0 = vp[0], f1 = vp[1], f2 = vp[2], f3 = vp[3];
        bf16x8 lo, hi;
        lo[0] = f2bf(f0.x); lo[1] = f2bf(f0.y); lo[2] = f2bf(f0.z); lo[3] = f2bf(f0.w);
        lo[4] = f2bf(f1.x); lo[5] = f2bf(f1.y); lo[6] = f2bf(f1.z); lo[7] = f2bf(f1.w);
        hi[0] = f2bf(f2.x); hi[1] = f2bf(f2.y); hi[2] = f2bf(f2.z); hi[3] = f2bf(f2.w);
        hi[4] = f2bf(f3.x); hi[5] = f2bf(f3.y); hi[6] = f2bf(f3.z); hi[7] = f2bf(f3.w);
        *(bf16x8*)(sV + SWZ64(v, cb))     = lo;
        *(bf16x8*)(sV + SWZ64(v, cb + 8)) = hi;
    }
    if (tid < 128) sZ[tid] = z[(bh * NC + c) * M + tid];   // already exclusive
    __syncthreads();  // B1: sPQt, sPKt, sV, sZ staged

    // C: Amat[n][j] = phiQ^T . phiK (masked), row-sums -> intra norm
    f32x4 accO[4], accC[4];
    for (int t = 0; t < 4; ++t) { accO[t] = (f32x4){0.f,0.f,0.f,0.f}; accC[t] = (f32x4){0.f,0.f,0.f,0.f}; }
    for (int mt = 0; mt < 4; ++mt) {
        bf16x8 aP = *(const bf16x8*)(sPQt + SWZ128(16 * wid + l16, 32 * mt + 8 * quad));
        for (int jt = 0; jt < 4; ++jt) {
            bf16x8 bK2 = *(const bf16x8*)(sPKt + SWZ128(16 * jt + l16, 32 * mt + 8 * quad));
            accC[jt] = MFMA16(aP, bK2, accC[jt]);
        }
    }
    float rsum[4] = {0.f, 0.f, 0.f, 0.f};
    for (int jt = 0; jt < 4; ++jt)
        for (int r = 0; r < 4; ++r) {
            const int n = 16 * wid + 4 * quad + r;
            const int j = 16 * jt + l16;
            const float av = (j <= n) ? accC[jt][r] : 0.f;
            rsum[r] += av;
            sAm[SWZ64(n, j)] = f2bf(av);
        }
    for (int r = 0; r < 4; ++r) {
        float s = rsum[r];
        s += __shfl_xor(s, 1); s += __shfl_xor(s, 2);
        s += __shfl_xor(s, 4); s += __shfl_xor(s, 8);
        if (l16 == 0) sNm[16 * wid + 4 * quad + r] = s;  // intra part of norm
    }

    // inter: accO += phiQ^T . S_excl (B-frags direct from global, L2-resident)
    {
        const ushort* Sb = St + (size_t)(bh * NC + c) * (DV * M);
        for (int mt = 0; mt < 4; ++mt) {
            bf16x8 aP = *(const bf16x8*)(sPQt + SWZ128(16 * wid + l16, 32 * mt + 8 * quad));
            for (int vt = 0; vt < 4; ++vt) {
                bf16x8 bS = *(const bf16x8*)(Sb + (16 * vt + l16) * M + 32 * mt + 8 * quad);
                accO[vt] = MFMA16(aP, bS, accO[vt]);
            }
        }
    }
    // norm inter part, wave-parallel: thread (n=tid&63, g=tid>>6) sums 32 m's
    {
        const int n = tid & 63, g = tid >> 6;
        float s = 0.f;
        for (int mm = 0; mm < 32; ++mm) {
            const int m = 32 * g + ((mm + n) & 31);      // rotate: spread banks
            s += bf2f(sPQt[SWZ128(n, m)]) * sZ[m];
        }
        sNmP[n * 4 + g] = s;
    }
    __syncthreads();  // B2: sAm, sNm(intra), sNmP ready; sPQt/sPKt now dead

    // E: accO += Amat . V   (intra-chunk causal)
    for (int jh = 0; jh < 2; ++jh) {
        bf16x8 aA = *(const bf16x8*)(sAm + SWZ64(16 * wid + l16, 32 * jh + 8 * quad));
        for (int vt = 0; vt < 4; ++vt) {
            bf16x8 bV = *(const bf16x8*)(sV + SWZ64(16 * vt + l16, 32 * jh + 8 * quad));
            accO[vt] = MFMA16(aA, bV, accO[vt]);
        }
    }
    if (tid < 64)
        sNm[tid] += sNmP[tid * 4] + sNmP[tid * 4 + 1] + sNmP[tid * 4 + 2] + sNmP[tid * 4 + 3];
    __syncthreads();  // B3: sNm final; pre-B2 sPQt/sPKt reads done -> sOut alias safe

    for (int vt = 0; vt < 4; ++vt)
        for (int r = 0; r < 4; ++r) {
            const int n = 16 * wid + 4 * quad + r, v = 16 * vt + l16;
            sOut[n * 65 + v] = accO[vt][r] / sNm[n];
        }
    __syncthreads();  // B4
    for (int i = tid; i < 4096; i += 256) {
        const int v = i >> 6, n = i & 63;
        out[(bh * DV + v) * NSEQ + n0 + n] = sOut[n * 65 + v];
    }
}

extern "C" void kernel_launch(void* const* d_in, const int* in_sizes, int n_in,
                              void* d_out, int out_size, void* d_ws, size_t ws_size,
                              hipStream_t stream)
{
    (void)in_sizes; (void)n_in; (void)out_size; (void)ws_size;
    const float* keys     = (const float*)d_in[0];
    const float* values   = (const float*)d_in[1];
    const float* queries  = (const float*)d_in[2];
    const float* features = (const float*)d_in[3];
    float* outp = (float*)d_out;

    // ws: St bf16 [BH][NC][DV][M] (4 MB) | z f32 [BH][NC][M] (128 KB)
    //   | pQ bf16 images (4 MB) | pK bf16 images (4 MB)
    char* w = (char*)d_ws;
    ushort* St  = (ushort*)w;
    float*  z   = (float*)(w + (size_t)4 * 1024 * 1024);
    ushort* pQg = (ushort*)(w + (size_t)4 * 1024 * 1024 + 128 * 1024);
    ushort* pKg = (ushort*)(w + (size_t)8 * 1024 * 1024 + 128 * 1024);

    favor_p1<<<dim3(BH * NC), dim3(256), 0, stream>>>(keys, values, queries, features,
                                                      St, z, pQg, pKg);
    favor_p2<<<dim3(260), dim3(256), 0, stream>>>(St, z);
    favor_p3<<<dim3(BH * NC), dim3(256), 0, stream>>>(values, St, z, pQg, pKg, outp);
}

// Round 5
// 88.488 us; speedup vs baseline: 1.6562x; 1.0086x over previous
//
#include <hip/hip_runtime.h>

// FAVOR+ causal linear attention — 3-kernel chunk-parallel pipeline,
// 2 blocks/CU everywhere (512-block grids) to overlap latency chains.
// BH=8, D=DV=64, N=2048, M=128, chunk C=64, NC=32.
//
// K1 (per chunk, split by m-half): phi-gen (3 orientations), chunk-local
//   S^T column-half + z half + swizzled phi image halves.
// K2: parallel exclusive prefix scan; each column split across 2 thread
//   halves (16 chunks each, carry via LDS) -> 2 blocks/CU.
// K3 (per chunk, split by v-half): Amat+norm (duplicated, cheap), inter
//   GEMM with register-hoisted S_excl B-frags, E GEMM, divide, store.
// All LDS tiles XOR-swizzled: col ^= (row&7)<<3.

#define BH 8
#define D 64
#define DV 64
#define NSEQ 2048
#define M 128
#define CHK 64
#define NC (NSEQ / CHK)
#define PHI_SCALE 0.08838834764831845f  // 1/sqrt(128)

typedef unsigned int uint;
typedef unsigned short ushort;
typedef __attribute__((ext_vector_type(8))) short bf16x8;
typedef __attribute__((ext_vector_type(4))) short bf16x4;
typedef __attribute__((ext_vector_type(4))) float f32x4;
#define MFMA16(a, b, c) __builtin_amdgcn_mfma_f32_16x16x32_bf16((a), (b), (c), 0, 0, 0)

__device__ __forceinline__ short f2bf(float x) {  // RNE truncate fp32->bf16
    uint u = __float_as_uint(x);
    u += 0x7fffu + ((u >> 16) & 1u);
    return (short)(u >> 16);
}
__device__ __forceinline__ float bf2f(short b) {
    return __uint_as_float(((uint)(ushort)b) << 16);
}

// element-index XOR swizzles for bf16 tiles (rows of 64 / 128 elements)
#define SWZ64(r, c)  ((r) * 64  + ((c) ^ (((r) & 7) << 3)))
#define SWZ128(r, c) ((r) * 128 + ((c) ^ (((r) & 7) << 3)))

// ---------------- Kernel 1: 512 blocks = (m-half, chunk) ----------------
__global__ __launch_bounds__(256, 2) void favor_p1(
    const float* __restrict__ keys, const float* __restrict__ values,
    const float* __restrict__ queries, const float* __restrict__ features,
    ushort* __restrict__ St, float* __restrict__ z,
    ushort* __restrict__ pQg, ushort* __restrict__ pKg)
{
    const int mh = blockIdx.x >> 8, cid = blockIdx.x & 255;   // halves 256 apart:
    const int bh = cid >> 5, c = cid & 31, n0 = c * CHK;      // same XCD slot
    const int tid = threadIdx.x;
    const int lane = tid & 63, wid = tid >> 6, quad = lane >> 4, l16 = lane & 15;

    __shared__ ulong2 smv[2048];               // 32 KB -> 2 blocks/CU
    short* sF    = (short*)smv;                // [64][64] bf16 F (this m-half)
    short* sPKmn = (short*)smv + 4096;         // [64][64] bf16 phiK[m_loc][n]
    short* sPQt  = (short*)smv + 8192;         // [64][64] bf16 phiQ^T cols m-half
    short* sPKt  = (short*)smv + 12288;        // [64][64] bf16 phiK^T cols m-half

    // F half-stage first (feeds the first barrier), then K/Q/V reg loads
    for (int k = 0; k < 4; ++k) {
        const int i = tid + 256 * k;           // float4 idx within half (1024)
        float4 f = ((const float4*)features)[mh * 1024 + i];
        const int e = 4 * i, row = e >> 6, col = e & 63;
        bf16x4 bq;
        bq[0] = f2bf(f.x); bq[1] = f2bf(f.y); bq[2] = f2bf(f.z); bq[3] = f2bf(f.w);
        *(bf16x4*)(sF + SWZ64(row, col)) = bq;
    }
    const float* Kb = keys    + bh * D * NSEQ + n0 + 16 * wid + l16;
    const float* Qb = queries + bh * D * NSEQ + n0 + 16 * wid + l16;
    bf16x8 bK[2], aQ[2], aV[2];
    for (int h = 0; h < 2; ++h)
        for (int j = 0; j < 8; ++j) {
            const int d = 32 * h + 8 * quad + j;
            bK[h][j] = f2bf(Kb[d * NSEQ]);     // B-frag phiK[m][n], A-frag phiK^T
            aQ[h][j] = f2bf(Qb[d * NSEQ]);     // A-frag phiQ^T
        }
    {
        const float* Vb = values + bh * DV * NSEQ + n0;
        for (int h = 0; h < 2; ++h) {
            const float4* vp = (const float4*)(Vb + (16 * wid + l16) * NSEQ + 32 * h + 8 * quad);
            float4 v0 = vp[0], v1 = vp[1];
            aV[h][0] = f2bf(v0.x); aV[h][1] = f2bf(v0.y);
            aV[h][2] = f2bf(v0.z); aV[h][3] = f2bf(v0.w);
            aV[h][4] = f2bf(v1.x); aV[h][5] = f2bf(v1.y);
            aV[h][6] = f2bf(v1.z); aV[h][7] = f2bf(v1.w);
        }
    }
    __syncthreads();  // B1: sF ready

    // phi generation for this m-half: one sF read feeds 3 MFMAs
    for (int mt = 0; mt < 4; ++mt) {
        f32x4 aMN = {0.f,0.f,0.f,0.f}, aQm = {0.f,0.f,0.f,0.f}, aKm = {0.f,0.f,0.f,0.f};
        for (int h = 0; h < 2; ++h) {
            bf16x8 fF = *(const bf16x8*)(sF + SWZ64(16 * mt + l16, 32 * h + 8 * quad));
            aMN = MFMA16(fF, bK[h], aMN);      // D[m][n] = F . K
            aQm = MFMA16(aQ[h], fF, aQm);      // D[n][m] = Q^T . F^T
            aKm = MFMA16(bK[h], fF, aKm);      // D[n][m] = K^T . F^T
        }
        for (int r = 0; r < 4; ++r) {
            const int mr = 16 * mt + 4 * quad + r;     // local m row
            sPKmn[SWZ64(mr, 16 * wid + l16)] = f2bf(fmaxf(aMN[r], 0.f) * PHI_SCALE);
            const int nr = 16 * wid + 4 * quad + r;    // row n
            sPQt[SWZ64(nr, 16 * mt + l16)] = f2bf(fmaxf(aQm[r], 0.f) * PHI_SCALE);
            sPKt[SWZ64(nr, 16 * mt + l16)] = f2bf(fmaxf(aKm[r], 0.f) * PHI_SCALE);
        }
    }
    __syncthreads();  // B2: phi tiles ready

    // z half (wave 0 only; waves 1-3 proceed to St MFMAs)
    if (tid < 64) {
        float s = 0.f;
        for (int n = 0; n < 64; ++n) s += bf2f(sPKmn[SWZ64(tid, (n + tid) & 63)]);
        z[(bh * NC + c) * M + mh * 64 + tid] = s;
    }

    // S^T[v][m-half] chunk-local -> global St
    {
        ushort* So = St + (size_t)(bh * NC + c) * (DV * M);
        for (int mt = 0; mt < 4; ++mt) {
            f32x4 acc = {0.f,0.f,0.f,0.f};
            for (int h = 0; h < 2; ++h) {
                bf16x8 bP = *(const bf16x8*)(sPKmn + SWZ64(16 * mt + l16, 32 * h + 8 * quad));
                acc = MFMA16(aV[h], bP, acc);
            }
            for (int r = 0; r < 4; ++r)
                So[(16 * wid + 4 * quad + r) * M + mh * 64 + 16 * mt + l16] =
                    (ushort)f2bf(acc[r]);
        }
    }

    // phi image halves -> global (row-half runs of 128B, coalesced)
    {
        ushort* pQc = pQg + (size_t)(bh * NC + c) * 8192;
        ushort* pKc = pKg + (size_t)(bh * NC + c) * 8192;
        const ulong2* sq = (const ulong2*)sPQt;
        const ulong2* sk = (const ulong2*)sPKt;
        for (int i = tid; i < 512; i += 256) {
            const int row = i >> 3, q = i & 7;
            ((ulong2*)pQc)[row * 16 + mh * 8 + q] = sq[i];
            ((ulong2*)pKc)[row * 16 + mh * 8 + q] = sk[i];
        }
    }
}

// ---------------- Kernel 2: exclusive prefix scans over chunks ----------------
// St: 512 blocks x 128 columns; each column split across 2 thread-halves
// (16 chunks each), carry via LDS -> same bitwise order, 2 blocks/CU.
__global__ __launch_bounds__(256, 2) void favor_p2(ushort* __restrict__ St,
                                                   float* __restrict__ z)
{
    __shared__ float carry[128];
    const int tid = threadIdx.x;
    if (blockIdx.x < 512) {
        const int col = blockIdx.x * 128 + (tid & 127);   // 0..65535
        const int half = tid >> 7;                        // wave-uniform
        const int bh = col >> 13, vm = col & 8191;
        ushort* p = St + (size_t)bh * NC * 8192 + vm;
        float vals[16];
        #pragma unroll
        for (int k = 0; k < 16; ++k) vals[k] = bf2f(p[(16 * half + k) * 8192]);
        if (half == 0) {
            float total = 0.f;
            #pragma unroll
            for (int k = 0; k < 16; ++k) total += vals[k];
            carry[tid] = total;
        }
        __syncthreads();
        float run = (half == 0) ? 0.f : carry[tid & 127];
        #pragma unroll
        for (int k = 0; k < 16; ++k) {
            p[(16 * half + k) * 8192] = (ushort)f2bf(run);
            run += vals[k];
        }
    } else {                                              // z: 4 blocks, 1024 cols
        const int i = (blockIdx.x - 512) * 256 + tid;
        const int bh = i >> 7, m = i & 127;
        float* p = z + bh * NC * M + m;
        float vals[NC];
        #pragma unroll
        for (int cc = 0; cc < NC; ++cc) vals[cc] = p[cc * M];
        float run = 0.f;
        #pragma unroll
        for (int cc = 0; cc < NC; ++cc) { p[cc * M] = run; run += vals[cc]; }
    }
}

// ---------------- Kernel 3: 512 blocks = (v-half, chunk) ----------------
__global__ __launch_bounds__(256, 2) void favor_p3(
    const float* __restrict__ values, const ushort* __restrict__ St,
    const float* __restrict__ z, const ushort* __restrict__ pQg,
    const ushort* __restrict__ pKg, float* __restrict__ out)
{
    const int vh = blockIdx.x >> 8, cid = blockIdx.x & 255;   // halves share L2
    const int bh = cid >> 5, c = cid & 31, n0 = c * CHK;
    const int tid = threadIdx.x;
    const int lane = tid & 63, wid = tid >> 6, quad = lane >> 4, l16 = lane & 15;

    __shared__ ulong2 smv[2928];                    // 46848 B -> 2 blocks/CU
    short* sPQt = (short*)smv;                      // [64][128] bf16 phiQ^T @0
    short* sPKt = (short*)smv + 8192;               // [64][128] bf16 phiK^T @16384
    short* sV   = (short*)smv + 16384;              // [32][64]  bf16 V half @32768
    short* sAm  = (short*)smv + 18432;              // [64][64]  bf16 Amat   @36864
    float* sNm  = (float*)((char*)smv + 45056);     // [64] norm
    float* sNmP = (float*)((char*)smv + 45312);     // [64][4] norm-inter partials
    float* sZ   = (float*)((char*)smv + 46336);     // [128] z_excl
    float* sOut = (float*)smv;                      // [64][33] f32 8448B (aliases
                                                    //  sPQt; all reads pre-B2)

    // hoist S_excl B-frags into registers (latency hides under staging)
    const ushort* Sb = St + (size_t)(bh * NC + c) * (DV * M);
    bf16x8 bS[4][2];
    #pragma unroll
    for (int mt = 0; mt < 4; ++mt)
        #pragma unroll
        for (int vt = 0; vt < 2; ++vt)
            bS[mt][vt] = *(const bf16x8*)(Sb + (vh * 32 + 16 * vt + l16) * M
                                             + 32 * mt + 8 * quad);

    // phi images global->LDS (coalesced 16B/lane; swizzle baked in)
    {
        const ulong2* pQc = (const ulong2*)(pQg + (size_t)(bh * NC + c) * 8192);
        const ulong2* pKc = (const ulong2*)(pKg + (size_t)(bh * NC + c) * 8192);
        ulong2* dq = (ulong2*)sPQt;
        ulong2* dk = (ulong2*)sPKt;
        for (int i = tid; i < 1024; i += 256) {
            dq[i] = pQc[i];
            dk[i] = pKc[i];
        }
    }
    // V half-stage: thread -> row tid>>3 (32 rows), 8 cols
    {
        const int vrow = tid >> 3, cb = (tid & 7) * 8;
        const float4* vp = (const float4*)(values + (bh * DV + vh * 32 + vrow) * NSEQ
                                                  + n0 + cb);
        float4 f0 = vp[0], f1 = vp[1];
        bf16x8 w;
        w[0] = f2bf(f0.x); w[1] = f2bf(f0.y); w[2] = f2bf(f0.z); w[3] = f2bf(f0.w);
        w[4] = f2bf(f1.x); w[5] = f2bf(f1.y); w[6] = f2bf(f1.z); w[7] = f2bf(f1.w);
        *(bf16x8*)(sV + SWZ64(vrow, cb)) = w;
    }
    if (tid < 128) sZ[tid] = z[(bh * NC + c) * M + tid];   // already exclusive
    __syncthreads();  // B1: sPQt, sPKt, sV, sZ staged

    // C: Amat[n][j] = phiQ^T . phiK (masked), row-sums -> intra norm (dup/half)
    f32x4 accO[2], accC[4];
    accO[0] = (f32x4){0.f,0.f,0.f,0.f}; accO[1] = (f32x4){0.f,0.f,0.f,0.f};
    for (int t = 0; t < 4; ++t) accC[t] = (f32x4){0.f,0.f,0.f,0.f};
    for (int mt = 0; mt < 4; ++mt) {
        bf16x8 aP = *(const bf16x8*)(sPQt + SWZ128(16 * wid + l16, 32 * mt + 8 * quad));
        for (int jt = 0; jt < 4; ++jt) {
            bf16x8 bK2 = *(const bf16x8*)(sPKt + SWZ128(16 * jt + l16, 32 * mt + 8 * quad));
            accC[jt] = MFMA16(aP, bK2, accC[jt]);
        }
    }
    float rsum[4] = {0.f, 0.f, 0.f, 0.f};
    for (int jt = 0; jt < 4; ++jt)
        for (int r = 0; r < 4; ++r) {
            const int n = 16 * wid + 4 * quad + r;
            const int j = 16 * jt + l16;
            const float av = (j <= n) ? accC[jt][r] : 0.f;
            rsum[r] += av;
            sAm[SWZ64(n, j)] = f2bf(av);
        }
    for (int r = 0; r < 4; ++r) {
        float s = rsum[r];
        s += __shfl_xor(s, 1); s += __shfl_xor(s, 2);
        s += __shfl_xor(s, 4); s += __shfl_xor(s, 8);
        if (l16 == 0) sNm[16 * wid + 4 * quad + r] = s;  // intra part of norm
    }

    // inter: accO += phiQ^T . S_excl (B-frags already in registers)
    for (int mt = 0; mt < 4; ++mt) {
        bf16x8 aP = *(const bf16x8*)(sPQt + SWZ128(16 * wid + l16, 32 * mt + 8 * quad));
        for (int vt = 0; vt < 2; ++vt)
            accO[vt] = MFMA16(aP, bS[mt][vt], accO[vt]);
    }
    // norm inter part, wave-parallel: thread (n=tid&63, g=tid>>6) sums 32 m's
    {
        const int n = tid & 63, g = tid >> 6;
        float s = 0.f;
        for (int mm = 0; mm < 32; ++mm) {
            const int m = 32 * g + ((mm + n) & 31);      // rotate: spread banks
            s += bf2f(sPQt[SWZ128(n, m)]) * sZ[m];
        }
        sNmP[n * 4 + g] = s;
    }
    __syncthreads();  // B2: sAm, sNm(intra), sNmP ready; sPQt/sPKt now dead

    // E: accO += Amat . V-half  (intra-chunk causal)
    for (int jh = 0; jh < 2; ++jh) {
        bf16x8 aA = *(const bf16x8*)(sAm + SWZ64(16 * wid + l16, 32 * jh + 8 * quad));
        for (int vt = 0; vt < 2; ++vt) {
            bf16x8 bV = *(const bf16x8*)(sV + SWZ64(16 * vt + l16, 32 * jh + 8 * quad));
            accO[vt] = MFMA16(aA, bV, accO[vt]);
        }
    }
    if (tid < 64)
        sNm[tid] += sNmP[tid * 4] + sNmP[tid * 4 + 1] + sNmP[tid * 4 + 2] + sNmP[tid * 4 + 3];
    __syncthreads();  // B3: sNm final; pre-B2 sPQt reads done -> sOut alias safe

    for (int vt = 0; vt < 2; ++vt)
        for (int r = 0; r < 4; ++r) {
            const int n = 16 * wid + 4 * quad + r, vl = 16 * vt + l16;
            sOut[n * 33 + vl] = accO[vt][r] / sNm[n];
        }
    __syncthreads();  // B4
    for (int i = tid; i < 2048; i += 256) {
        const int vl = i >> 6, n = i & 63;
        out[(bh * DV + vh * 32 + vl) * NSEQ + n0 + n] = sOut[n * 33 + vl];
    }
}

extern "C" void kernel_launch(void* const* d_in, const int* in_sizes, int n_in,
                              void* d_out, int out_size, void* d_ws, size_t ws_size,
                              hipStream_t stream)
{
    (void)in_sizes; (void)n_in; (void)out_size; (void)ws_size;
    const float* keys     = (const float*)d_in[0];
    const float* values   = (const float*)d_in[1];
    const float* queries  = (const float*)d_in[2];
    const float* features = (const float*)d_in[3];
    float* outp = (float*)d_out;

    // ws: St bf16 [BH][NC][DV][M] (4 MB) | z f32 [BH][NC][M] (128 KB)
    //   | pQ bf16 images (4 MB) | pK bf16 images (4 MB)
    char* w = (char*)d_ws;
    ushort* St  = (ushort*)w;
    float*  z   = (float*)(w + (size_t)4 * 1024 * 1024);
    ushort* pQg = (ushort*)(w + (size_t)4 * 1024 * 1024 + 128 * 1024);
    ushort* pKg = (ushort*)(w + (size_t)8 * 1024 * 1024 + 128 * 1024);

    favor_p1<<<dim3(512), dim3(256), 0, stream>>>(keys, values, queries, features,
                                                  St, z, pQg, pKg);
    favor_p2<<<dim3(516), dim3(256), 0, stream>>>(St, z);
    favor_p3<<<dim3(512), dim3(256), 0, stream>>>(values, St, z, pQg, pKg, outp);
}